// Round 5
// baseline (895.100 us; speedup 1.0000x reference)
//
#include <hip/hip_runtime.h>
#include <hip/hip_bf16.h>

typedef __attribute__((ext_vector_type(8))) short short8;
typedef __attribute__((ext_vector_type(4))) float floatx4;

#define H 16
#define BB 2
#define SS 2048
#define DM 1024
#define DK 64

__device__ __forceinline__ unsigned short f2bf(float f) {
  union { float f; unsigned int u; } x; x.f = f;
  unsigned int r = (x.u + 0x7fffu + ((x.u >> 16) & 1u)) >> 16;
  return (unsigned short)r;
}
__device__ __forceinline__ float bf2f(unsigned short h) {
  union { unsigned int u; float f; } x; x.u = (unsigned int)h << 16;
  return x.f;
}
__device__ __forceinline__ void gld16(const unsigned short* g, unsigned short* l) {
  __builtin_amdgcn_global_load_lds(
      (const __attribute__((address_space(1))) unsigned int*)(g),
      (__attribute__((address_space(3))) unsigned int*)(l), 16, 0, 0);
}

// ---------------------------------------------------------------------------
// fp32 -> bf16 conversion for Q, K, V (each 4096 x 1024)
// ---------------------------------------------------------------------------
__global__ __launch_bounds__(256) void convert_qkv(
    const float* __restrict__ Q, const float* __restrict__ K, const float* __restrict__ V,
    unsigned short* __restrict__ Qb, unsigned short* __restrict__ Kb,
    unsigned short* __restrict__ Vb) {
  const float* in; unsigned short* out;
  int z = blockIdx.y;
  if (z == 0)      { in = Q; out = Qb; }
  else if (z == 1) { in = K; out = Kb; }
  else             { in = V; out = Vb; }
  size_t i = ((size_t)blockIdx.x * 256 + threadIdx.x) * 4;
  float4 v = *(const float4*)&in[i];
  ushort4 o;
  o.x = f2bf(v.x); o.y = f2bf(v.y); o.z = f2bf(v.z); o.w = f2bf(v.w);
  *(ushort4*)&out[i] = o;
}

// ---------------------------------------------------------------------------
// Weight repack + fp32->bf16: Wq/Wk/Wv (H, DM, 64) -> W_t[(h*64+k)][d]
//                             Wo (1024, 1024)      -> Wo_t[n][k] = Wo[k][n]
// ---------------------------------------------------------------------------
__global__ __launch_bounds__(256) void repack_w(
    const float* __restrict__ Wq, const float* __restrict__ Wk,
    const float* __restrict__ Wv, const float* __restrict__ Wo,
    unsigned short* __restrict__ Wq_t, unsigned short* __restrict__ Wk_t,
    unsigned short* __restrict__ Wv_t, unsigned short* __restrict__ Wo_t) {
  int z = blockIdx.z;
  int bx = blockIdx.x, by = blockIdx.y;
  int t = threadIdx.x;
  const float* in;
  unsigned short* out;
  if (z == 0)      { in = Wq; out = Wq_t; }
  else if (z == 1) { in = Wk; out = Wk_t; }
  else if (z == 2) { in = Wv; out = Wv_t; }
  else             { in = Wo; out = Wo_t; }
  #pragma unroll
  for (int i = 0; i < 16; i++) {
    int o = t + i * 256;          // 0..4095 within 64x64 tile
    int r = o >> 6, cloc = o & 63;
    if (z < 3) {
      out[(bx * 64 + r) * 1024 + by * 64 + cloc] =
          f2bf(in[bx * 65536 + (by * 64 + cloc) * 64 + r]);
    } else {
      out[(bx * 64 + r) * 1024 + by * 64 + cloc] =
          f2bf(in[(by * 64 + cloc) * 1024 + bx * 64 + r]);
    }
  }
}

// ---------------------------------------------------------------------------
// C (MxN, row-major) = A (MxK, row-major, bf16) * Bt^T  (Bt is NxK, bf16)
// global_load_lds dwordx4 staging, BK=64, T2 XOR swizzle:
//   LDS dest linear (gld16 requirement); global SOURCE chunk col ^= row&7;
//   ds_read_b128 applies the same XOR -> conflict-free fragment reads.
// Tile 128(M) x 64(N), 256 threads (4 waves, each 64x32 out). Grid (N/64, M/128).
// ---------------------------------------------------------------------------
__global__ __launch_bounds__(256) void gemm_bt(
    const unsigned short* __restrict__ A, const unsigned short* __restrict__ Bt,
    unsigned short* __restrict__ C, float* __restrict__ Cf, int M, int N, int K) {
  __shared__ __align__(16) unsigned short a_lds[128 * 64];
  __shared__ __align__(16) unsigned short b_lds[64 * 64];
  const int bn = blockIdx.x * 64, bm = blockIdx.y * 128;
  const int t = threadIdx.x;
  const int wave = t >> 6, lane = t & 63;
  const int quad = lane >> 4, l15 = lane & 15;
  const int wm = (wave & 1) * 64, wn = (wave >> 1) * 32;
  floatx4 acc[4][2] = {};
  for (int kt = 0; kt < K; kt += 64) {
    __syncthreads();
    // A tile 128x64 (16KB): 4 chunks/thread; source col pre-swizzled by row&7
    #pragma unroll
    for (int it = 0; it < 4; it++) {
      int c = t + it * 256;
      int r = c >> 3, ck = c & 7;
      gld16(&A[(size_t)(bm + r) * K + kt + ((ck ^ (r & 7)) * 8)], &a_lds[c * 8]);
    }
    // B tile 64x64 (8KB): 2 chunks/thread
    #pragma unroll
    for (int it = 0; it < 2; it++) {
      int c = t + it * 256;
      int r = c >> 3, ck = c & 7;
      gld16(&Bt[(size_t)(bn + r) * K + kt + ((ck ^ (r & 7)) * 8)], &b_lds[c * 8]);
    }
    __syncthreads();
    #pragma unroll
    for (int kk = 0; kk < 2; kk++) {
      short8 af[4], bfr[2];
      #pragma unroll
      for (int mt = 0; mt < 4; mt++) {
        int r = wm + mt * 16 + l15;
        af[mt] = *(const short8*)&a_lds[r * 64 + (((kk * 4 + quad) ^ (r & 7)) * 8)];
      }
      #pragma unroll
      for (int nt = 0; nt < 2; nt++) {
        int r = wn + nt * 16 + l15;
        bfr[nt] = *(const short8*)&b_lds[r * 64 + (((kk * 4 + quad) ^ (r & 7)) * 8)];
      }
      #pragma unroll
      for (int mt = 0; mt < 4; mt++)
        #pragma unroll
        for (int nt = 0; nt < 2; nt++)
          acc[mt][nt] = __builtin_amdgcn_mfma_f32_16x16x32_bf16(af[mt], bfr[nt], acc[mt][nt], 0, 0, 0);
    }
  }
  if (Cf) {
    #pragma unroll
    for (int mt = 0; mt < 4; mt++)
      #pragma unroll
      for (int nt = 0; nt < 2; nt++)
        #pragma unroll
        for (int r = 0; r < 4; r++) {
          int row = bm + wm + mt * 16 + quad * 4 + r;
          int col = bn + wn + nt * 16 + l15;
          Cf[(size_t)row * N + col] = acc[mt][nt][r];
        }
  } else {
    #pragma unroll
    for (int mt = 0; mt < 4; mt++)
      #pragma unroll
      for (int nt = 0; nt < 2; nt++)
        #pragma unroll
        for (int r = 0; r < 4; r++) {
          int row = bm + wm + mt * 16 + quad * 4 + r;
          int col = bn + wn + nt * 16 + l15;
          C[(size_t)row * N + col] = f2bf(acc[mt][nt][r]);
        }
  }
}

// ---------------------------------------------------------------------------
// Attention, 2-pass recompute, 128-key tiles, LDS reuse (K tile -> P tile):
//   pass 1 (x16): stage K(128x64) -> 16 MFMA QK -> rowsum += m*exp2
//   pass 2 (x16): stage K+V^T -> QK into regs (sv[8]) -> barrier ->
//                 p = m*exp2*rinv overwrites k_lds -> barrier ->
//                 coalesced fp32 attns write + PV accumulate.
// LDS ~38KB -> 4 blocks/CU. Strides 72/136 (== 4 mod 32 dw) -> 2-way (free).
// ---------------------------------------------------------------------------
__global__ __launch_bounds__(256) void attn_kernel(
    const unsigned short* __restrict__ q2, const unsigned short* __restrict__ k2,
    const unsigned short* __restrict__ vt, const void* __restrict__ mask,
    float* __restrict__ attns, unsigned short* __restrict__ ctx) {
  __shared__ __align__(16) unsigned short k_lds[128 * 72];   // K tile; P tile in pass 2; Q at entry
  __shared__ __align__(16) unsigned short vt_lds[64 * 136];  // V^T tile (64 n x 128 keys)
  __shared__ unsigned char masku8[SS];
  __shared__ float rowsum_inv[64];
  __shared__ int s_fp32, s_byte2, s_gt1;
  const int qt = blockIdx.x, b = blockIdx.y, h = blockIdx.z;
  const int t = threadIdx.x;
  const int wave = t >> 6, lane = t & 63;
  const int quad = lane >> 4, l15 = lane & 15;

  // ---- mask dtype detection: scan first 1024 words (4KB, safe for all widths)
  if (t == 0) { s_fp32 = 1; s_byte2 = 0; s_gt1 = 0; }
  __syncthreads();
  {
    const unsigned int* mw = (const unsigned int*)mask;
    int f_fp32 = 1, f_byte2 = 0, f_gt1 = 0;
    for (int i = t; i < 1024; i += 256) {
      unsigned int w = mw[i];
      if (!(w == 0u || w == 0x3F800000u)) f_fp32 = 0;
      if (((w & 0xFFu) > 1u) || (((w >> 8) & 0xFFu) > 1u) ||
          (((w >> 16) & 0xFFu) > 1u) || ((w >> 24) > 1u)) f_byte2 = 1;
      if (w > 1u) f_gt1 = 1;
    }
    if (!f_fp32) atomicAnd(&s_fp32, 0);
    if (f_byte2) atomicOr(&s_byte2, 1);
    if (f_gt1)  atomicOr(&s_gt1, 1);
  }
  __syncthreads();
  {
    const unsigned int*   mw = (const unsigned int*)mask;
    const unsigned short* mh = (const unsigned short*)mask;
    const unsigned char*  mb = (const unsigned char*)mask;
    int mode = s_fp32 ? 0 : (s_byte2 ? 1 : (s_gt1 ? 2 : 3));
    for (int i = t; i < SS; i += 256) {
      int idx = b * SS + i;
      bool mv;
      if (mode == 0)      mv = mw[idx] != 0u;   // fp32 (or all-false)
      else if (mode == 1) mv = mh[idx] != 0u;   // bf16/f16
      else if (mode == 2) mv = mb[idx] != 0u;   // int8 / bool
      else                mv = mw[idx] != 0u;   // int32
      masku8[i] = mv ? 1 : 0;
    }
  }

  // stage q tile (64 x 64) into k_lds (stride 72)
  {
    int c = t;
    #pragma unroll
    for (int it = 0; it < 2; it++, c += 256) {
      int r = c >> 3, cc = (c & 7) * 8;
      *(uint4*)&k_lds[r * 72 + cc] =
          *(const uint4*)&q2[(size_t)(b * SS + qt * 64 + r) * DM + h * DK + cc];
    }
  }
  __syncthreads();
  short8 aq0 = *(const short8*)&k_lds[(wave * 16 + l15) * 72 + quad * 8];
  short8 aq1 = *(const short8*)&k_lds[(wave * 16 + l15) * 72 + 32 + quad * 8];

  const float cexp = 0.18033688011112042f;  // log2(e) / sqrt(64)
  float rs[4] = {0.f, 0.f, 0.f, 0.f};

  // ---- pass 1: row sums (128-key tiles) ----
  for (int kt = 0; kt < 16; kt++) {
    __syncthreads();
    {
      int c = t;
      #pragma unroll
      for (int it = 0; it < 4; it++, c += 256) {   // K tile: 128 keys x 64 d
        int r = c >> 3, cc = (c & 7) * 8;
        *(uint4*)&k_lds[r * 72 + cc] =
            *(const uint4*)&k2[(size_t)(b * SS + kt * 128 + r) * DM + h * DK + cc];
      }
    }
    __syncthreads();
    #pragma unroll
    for (int ct = 0; ct < 8; ct++) {
      floatx4 s = {};
      short8 bk0 = *(const short8*)&k_lds[(ct * 16 + l15) * 72 + quad * 8];
      short8 bk1 = *(const short8*)&k_lds[(ct * 16 + l15) * 72 + 32 + quad * 8];
      s = __builtin_amdgcn_mfma_f32_16x16x32_bf16(aq0, bk0, s, 0, 0, 0);
      s = __builtin_amdgcn_mfma_f32_16x16x32_bf16(aq1, bk1, s, 0, 0, 0);
      float m = (float)masku8[kt * 128 + ct * 16 + l15];
      #pragma unroll
      for (int r = 0; r < 4; r++) rs[r] += m * exp2f(s[r] * cexp);
    }
  }
  #pragma unroll
  for (int r = 0; r < 4; r++) {
    rs[r] += __shfl_xor(rs[r], 1);
    rs[r] += __shfl_xor(rs[r], 2);
    rs[r] += __shfl_xor(rs[r], 4);
    rs[r] += __shfl_xor(rs[r], 8);
  }
  if (l15 == 0) {
    #pragma unroll
    for (int r = 0; r < 4; r++)
      rowsum_inv[wave * 16 + quad * 4 + r] = rs[r] > 0.f ? 1.0f / rs[r] : 0.f;
  }
  __syncthreads();
  float rinv[4];
  #pragma unroll
  for (int r = 0; r < 4; r++) rinv[r] = rowsum_inv[wave * 16 + quad * 4 + r];

  floatx4 cacc[4] = {};
  const size_t attn_base = ((size_t)(h * BB + b) * SS + qt * 64) * SS;

  // ---- pass 2: recompute, write normalized attn (fp32, once), accumulate PV ----
  for (int kt = 0; kt < 16; kt++) {
    __syncthreads();
    {
      int c = t;
      #pragma unroll
      for (int it = 0; it < 4; it++, c += 256) {   // K tile: 128 x 64
        int r = c >> 3, cc = (c & 7) * 8;
        *(uint4*)&k_lds[r * 72 + cc] =
            *(const uint4*)&k2[(size_t)(b * SS + kt * 128 + r) * DM + h * DK + cc];
      }
      c = t;
      #pragma unroll
      for (int it = 0; it < 4; it++, c += 256) {   // V^T tile: 64 n x 128 keys
        int n = c >> 4, cc = (c & 15) * 8;
        *(uint4*)&vt_lds[n * 136 + cc] =
            *(const uint4*)&vt[(size_t)(h * DK + n) * (BB * SS) + b * SS + kt * 128 + cc];
      }
    }
    __syncthreads();
    // QK into registers (k_lds becomes dead after this)
    floatx4 sv[8];
    #pragma unroll
    for (int ct = 0; ct < 8; ct++) {
      floatx4 s = {};
      short8 bk0 = *(const short8*)&k_lds[(ct * 16 + l15) * 72 + quad * 8];
      short8 bk1 = *(const short8*)&k_lds[(ct * 16 + l15) * 72 + 32 + quad * 8];
      s = __builtin_amdgcn_mfma_f32_16x16x32_bf16(aq0, bk0, s, 0, 0, 0);
      sv[ct] = __builtin_amdgcn_mfma_f32_16x16x32_bf16(aq1, bk1, s, 0, 0, 0);
    }
    __syncthreads();
    // p overwrites k_lds as P tile [64][136]
    #pragma unroll
    for (int ct = 0; ct < 8; ct++) {
      float m = (float)masku8[kt * 128 + ct * 16 + l15];
      #pragma unroll
      for (int r = 0; r < 4; r++) {
        float p = m * exp2f(sv[ct][r] * cexp) * rinv[r];      // normalized
        k_lds[(wave * 16 + quad * 4 + r) * 136 + ct * 16 + l15] = f2bf(p);
      }
    }
    __syncthreads();
    // coalesced normalized fp32 attn write from LDS (64x128 tile, 8 float4/thread)
    {
      int c = t;
      #pragma unroll
      for (int it = 0; it < 8; it++, c += 256) {
        int r = c >> 5, fc = (c & 31) * 4;
        ushort4 u = *(const ushort4*)&k_lds[r * 136 + fc];
        float4 f;
        f.x = bf2f(u.x); f.y = bf2f(u.y);
        f.z = bf2f(u.z); f.w = bf2f(u.w);
        *(float4*)&attns[attn_base + (size_t)r * SS + kt * 128 + fc] = f;
      }
    }
    // PV: cacc += P(64x128) @ V(128x64)
    #pragma unroll
    for (int ks = 0; ks < 4; ks++) {
      short8 ap = *(const short8*)&k_lds[(wave * 16 + l15) * 136 + ks * 32 + quad * 8];
      #pragma unroll
      for (int ct = 0; ct < 4; ct++) {
        short8 bv = *(const short8*)&vt_lds[(ct * 16 + l15) * 136 + ks * 32 + quad * 8];
        cacc[ct] = __builtin_amdgcn_mfma_f32_16x16x32_bf16(ap, bv, cacc[ct], 0, 0, 0);
      }
    }
  }
  // epilogue: ctx[(b*S + q)*1024 + h*64 + n]  (bf16, already normalized)
  #pragma unroll
  for (int ct = 0; ct < 4; ct++)
    #pragma unroll
    for (int r = 0; r < 4; r++) {
      int row = b * SS + qt * 64 + wave * 16 + quad * 4 + r;
      int col = h * DK + ct * 16 + l15;
      ctx[(size_t)row * DM + col] = f2bf(cacc[ct][r]);
    }
}

// ---------------------------------------------------------------------------
extern "C" void kernel_launch(void* const* d_in, const int* in_sizes, int n_in,
                              void* d_out, int out_size, void* d_ws, size_t ws_size,
                              hipStream_t stream) {
  (void)in_sizes; (void)n_in; (void)out_size; (void)ws_size;
  const float* Q  = (const float*)d_in[0];
  const float* K  = (const float*)d_in[1];
  const float* V  = (const float*)d_in[2];
  const float* Wq = (const float*)d_in[3];
  const float* Wk = (const float*)d_in[4];
  const float* Wv = (const float*)d_in[5];
  const float* Wo = (const float*)d_in[6];
  const void* mask = d_in[7];

  float* out   = (float*)d_out;
  float* attns = out + (size_t)BB * SS * DM;  // after the 2x2048x1024 output

  char* ws = (char*)d_ws;
  unsigned short* Qb   = (unsigned short*)(ws);
  unsigned short* Kb   = (unsigned short*)(ws + (size_t)(8u  << 20));
  unsigned short* Vb   = (unsigned short*)(ws + (size_t)(16u << 20));
  unsigned short* q2   = (unsigned short*)(ws + (size_t)(24u << 20));
  unsigned short* k2   = (unsigned short*)(ws + (size_t)(32u << 20));
  unsigned short* vt   = (unsigned short*)(ws + (size_t)(40u << 20));
  unsigned short* ctx  = (unsigned short*)(ws + (size_t)(48u << 20));
  unsigned short* Wq_t = (unsigned short*)(ws + (size_t)(56u << 20));
  unsigned short* Wk_t = (unsigned short*)(ws + (size_t)(58u << 20));
  unsigned short* Wv_t = (unsigned short*)(ws + (size_t)(60u << 20));
  unsigned short* Wo_t = (unsigned short*)(ws + (size_t)(62u << 20));

  convert_qkv<<<dim3(4096, 3), 256, 0, stream>>>(Q, K, V, Qb, Kb, Vb);
  repack_w<<<dim3(16, 16, 4), 256, 0, stream>>>(Wq, Wk, Wv, Wo, Wq_t, Wk_t, Wv_t, Wo_t);
  gemm_bt<<<dim3(16, 32), 256, 0, stream>>>(Qb, Wq_t, q2, nullptr, 4096, 1024, 1024);
  gemm_bt<<<dim3(16, 32), 256, 0, stream>>>(Kb, Wk_t, k2, nullptr, 4096, 1024, 1024);
  gemm_bt<<<dim3(64, 8), 256, 0, stream>>>(Wv_t, Vb, vt, nullptr, 1024, 4096, 1024);
  attn_kernel<<<dim3(32, 2, 16), 256, 0, stream>>>(q2, k2, vt, mask, attns, ctx);
  gemm_bt<<<dim3(16, 32), 256, 0, stream>>>(ctx, Wo_t, nullptr, out, 4096, 1024, 1024);
}

// Round 14
// 782.757 us; speedup vs baseline: 1.1435x; 1.1435x over previous
//
#include <hip/hip_runtime.h>
#include <hip/hip_bf16.h>

typedef __attribute__((ext_vector_type(8))) short short8;
typedef __attribute__((ext_vector_type(4))) float floatx4;

#define H 16
#define BB 2
#define SS 2048
#define DM 1024
#define DK 64

__device__ __forceinline__ unsigned short f2bf(float f) {
  union { float f; unsigned int u; } x; x.f = f;
  unsigned int r = (x.u + 0x7fffu + ((x.u >> 16) & 1u)) >> 16;
  return (unsigned short)r;
}
__device__ __forceinline__ float bf2f(unsigned short h) {
  union { unsigned int u; float f; } x; x.u = (unsigned int)h << 16;
  return x.f;
}
__device__ __forceinline__ void gld16(const unsigned short* g, unsigned short* l) {
  __builtin_amdgcn_global_load_lds(
      (const __attribute__((address_space(1))) unsigned int*)(g),
      (__attribute__((address_space(3))) unsigned int*)(l), 16, 0, 0);
}

// ---------------------------------------------------------------------------
// fp32 -> bf16 conversion for Q, K, V (each 4096 x 1024)
// ---------------------------------------------------------------------------
__global__ __launch_bounds__(256) void convert_qkv(
    const float* __restrict__ Q, const float* __restrict__ K, const float* __restrict__ V,
    unsigned short* __restrict__ Qb, unsigned short* __restrict__ Kb,
    unsigned short* __restrict__ Vb) {
  const float* in; unsigned short* out;
  int z = blockIdx.y;
  if (z == 0)      { in = Q; out = Qb; }
  else if (z == 1) { in = K; out = Kb; }
  else             { in = V; out = Vb; }
  size_t i = ((size_t)blockIdx.x * 256 + threadIdx.x) * 4;
  float4 v = *(const float4*)&in[i];
  ushort4 o;
  o.x = f2bf(v.x); o.y = f2bf(v.y); o.z = f2bf(v.z); o.w = f2bf(v.w);
  *(ushort4*)&out[i] = o;
}

// ---------------------------------------------------------------------------
// Weight repack + fp32->bf16: Wq/Wk/Wv (H, DM, 64) -> W_t[(h*64+k)][d]
//                             Wo (1024, 1024)      -> Wo_t[n][k] = Wo[k][n]
// ---------------------------------------------------------------------------
__global__ __launch_bounds__(256) void repack_w(
    const float* __restrict__ Wq, const float* __restrict__ Wk,
    const float* __restrict__ Wv, const float* __restrict__ Wo,
    unsigned short* __restrict__ Wq_t, unsigned short* __restrict__ Wk_t,
    unsigned short* __restrict__ Wv_t, unsigned short* __restrict__ Wo_t) {
  int z = blockIdx.z;
  int bx = blockIdx.x, by = blockIdx.y;
  int t = threadIdx.x;
  const float* in;
  unsigned short* out;
  if (z == 0)      { in = Wq; out = Wq_t; }
  else if (z == 1) { in = Wk; out = Wk_t; }
  else if (z == 2) { in = Wv; out = Wv_t; }
  else             { in = Wo; out = Wo_t; }
  #pragma unroll
  for (int i = 0; i < 16; i++) {
    int o = t + i * 256;          // 0..4095 within 64x64 tile
    int r = o >> 6, cloc = o & 63;
    if (z < 3) {
      out[(bx * 64 + r) * 1024 + by * 64 + cloc] =
          f2bf(in[bx * 65536 + (by * 64 + cloc) * 64 + r]);
    } else {
      out[(bx * 64 + r) * 1024 + by * 64 + cloc] =
          f2bf(in[(by * 64 + cloc) * 1024 + bx * 64 + r]);
    }
  }
}

// ---------------------------------------------------------------------------
// C (MxN, row-major) = A (MxK, row-major, bf16) * Bt^T  (Bt is NxK, bf16)
// global_load_lds dwordx4 staging, BK=64, T2 XOR swizzle:
//   LDS dest linear (gld16 requirement); global SOURCE chunk col ^= row&7;
//   ds_read_b128 applies the same XOR -> conflict-free fragment reads.
// Tile 128(M) x 64(N), 256 threads (4 waves, each 64x32 out). Grid (N/64, M/128).
// ---------------------------------------------------------------------------
__global__ __launch_bounds__(256) void gemm_bt(
    const unsigned short* __restrict__ A, const unsigned short* __restrict__ Bt,
    unsigned short* __restrict__ C, float* __restrict__ Cf, int M, int N, int K) {
  __shared__ __align__(16) unsigned short a_lds[128 * 64];
  __shared__ __align__(16) unsigned short b_lds[64 * 64];
  const int bn = blockIdx.x * 64, bm = blockIdx.y * 128;
  const int t = threadIdx.x;
  const int wave = t >> 6, lane = t & 63;
  const int quad = lane >> 4, l15 = lane & 15;
  const int wm = (wave & 1) * 64, wn = (wave >> 1) * 32;
  floatx4 acc[4][2] = {};
  for (int kt = 0; kt < K; kt += 64) {
    __syncthreads();
    // A tile 128x64 (16KB): 4 chunks/thread; source col pre-swizzled by row&7
    #pragma unroll
    for (int it = 0; it < 4; it++) {
      int c = t + it * 256;
      int r = c >> 3, ck = c & 7;
      gld16(&A[(size_t)(bm + r) * K + kt + ((ck ^ (r & 7)) * 8)], &a_lds[c * 8]);
    }
    // B tile 64x64 (8KB): 2 chunks/thread
    #pragma unroll
    for (int it = 0; it < 2; it++) {
      int c = t + it * 256;
      int r = c >> 3, ck = c & 7;
      gld16(&Bt[(size_t)(bn + r) * K + kt + ((ck ^ (r & 7)) * 8)], &b_lds[c * 8]);
    }
    __syncthreads();
    #pragma unroll
    for (int kk = 0; kk < 2; kk++) {
      short8 af[4], bfr[2];
      #pragma unroll
      for (int mt = 0; mt < 4; mt++) {
        int r = wm + mt * 16 + l15;
        af[mt] = *(const short8*)&a_lds[r * 64 + (((kk * 4 + quad) ^ (r & 7)) * 8)];
      }
      #pragma unroll
      for (int nt = 0; nt < 2; nt++) {
        int r = wn + nt * 16 + l15;
        bfr[nt] = *(const short8*)&b_lds[r * 64 + (((kk * 4 + quad) ^ (r & 7)) * 8)];
      }
      #pragma unroll
      for (int mt = 0; mt < 4; mt++)
        #pragma unroll
        for (int nt = 0; nt < 2; nt++)
          acc[mt][nt] = __builtin_amdgcn_mfma_f32_16x16x32_bf16(af[mt], bfr[nt], acc[mt][nt], 0, 0, 0);
    }
  }
  if (Cf) {
    #pragma unroll
    for (int mt = 0; mt < 4; mt++)
      #pragma unroll
      for (int nt = 0; nt < 2; nt++)
        #pragma unroll
        for (int r = 0; r < 4; r++) {
          int row = bm + wm + mt * 16 + quad * 4 + r;
          int col = bn + wn + nt * 16 + l15;
          Cf[(size_t)row * N + col] = acc[mt][nt][r];
        }
  } else {
    #pragma unroll
    for (int mt = 0; mt < 4; mt++)
      #pragma unroll
      for (int nt = 0; nt < 2; nt++)
        #pragma unroll
        for (int r = 0; r < 4; r++) {
          int row = bm + wm + mt * 16 + quad * 4 + r;
          int col = bn + wn + nt * 16 + l15;
          C[(size_t)row * N + col] = f2bf(acc[mt][nt][r]);
        }
  }
}

// ---------------------------------------------------------------------------
// Attention, 2-pass recompute, low-pressure (round-3 structure, improved):
//   One 192-row x 72-stride union buffer:
//     pass 1: rows 0..127 = K (128 keys/stage, 16 stages -> half the barriers)
//     pass 2: rows 0..63 = K, rows 64..127 = V^T, rows 128..191 = P
//   pass 2 (x32, KVBLK=64): stage K+V -> s -> p (write direct to P rows,
//     no register staging) -> attns fp32 write + PV.
// LDS ~30KB -> 5 blocks/CU; no sv[] array -> VGPR ~90 -> 5 waves/SIMD.
// Stride 72 (== 4 mod 32 dw): b128 fragment reads 2 lanes/bank (free).
// ---------------------------------------------------------------------------
#define VB (64 * 72)    // V^T base row offset in buf
#define PB (128 * 72)   // P base row offset in buf
__global__ __launch_bounds__(256) void attn_kernel(
    const unsigned short* __restrict__ q2, const unsigned short* __restrict__ k2,
    const unsigned short* __restrict__ vt, const void* __restrict__ mask,
    float* __restrict__ attns, unsigned short* __restrict__ ctx) {
  __shared__ __align__(16) unsigned short buf[192 * 72];
  __shared__ unsigned char masku8[SS];
  __shared__ float rowsum_inv[64];
  __shared__ int s_fp32, s_byte2, s_gt1;
  const int qt = blockIdx.x, b = blockIdx.y, h = blockIdx.z;
  const int t = threadIdx.x;
  const int wave = t >> 6, lane = t & 63;
  const int quad = lane >> 4, l15 = lane & 15;

  // ---- mask dtype detection: scan first 1024 words (4KB, safe for all widths)
  if (t == 0) { s_fp32 = 1; s_byte2 = 0; s_gt1 = 0; }
  __syncthreads();
  {
    const unsigned int* mw = (const unsigned int*)mask;
    int f_fp32 = 1, f_byte2 = 0, f_gt1 = 0;
    for (int i = t; i < 1024; i += 256) {
      unsigned int w = mw[i];
      if (!(w == 0u || w == 0x3F800000u)) f_fp32 = 0;
      if (((w & 0xFFu) > 1u) || (((w >> 8) & 0xFFu) > 1u) ||
          (((w >> 16) & 0xFFu) > 1u) || ((w >> 24) > 1u)) f_byte2 = 1;
      if (w > 1u) f_gt1 = 1;
    }
    if (!f_fp32) atomicAnd(&s_fp32, 0);
    if (f_byte2) atomicOr(&s_byte2, 1);
    if (f_gt1)  atomicOr(&s_gt1, 1);
  }
  __syncthreads();
  {
    const unsigned int*   mw = (const unsigned int*)mask;
    const unsigned short* mh = (const unsigned short*)mask;
    const unsigned char*  mb = (const unsigned char*)mask;
    int mode = s_fp32 ? 0 : (s_byte2 ? 1 : (s_gt1 ? 2 : 3));
    for (int i = t; i < SS; i += 256) {
      int idx = b * SS + i;
      bool mv;
      if (mode == 0)      mv = mw[idx] != 0u;   // fp32 (or all-false)
      else if (mode == 1) mv = mh[idx] != 0u;   // bf16/f16
      else if (mode == 2) mv = mb[idx] != 0u;   // int8 / bool
      else                mv = mw[idx] != 0u;   // int32
      masku8[i] = mv ? 1 : 0;
    }
  }

  // stage q tile (64 x 64) into buf rows 0..63 (stride 72)
  {
    int c = t;
    #pragma unroll
    for (int it = 0; it < 2; it++, c += 256) {
      int r = c >> 3, cc = (c & 7) * 8;
      *(uint4*)&buf[r * 72 + cc] =
          *(const uint4*)&q2[(size_t)(b * SS + qt * 64 + r) * DM + h * DK + cc];
    }
  }
  __syncthreads();
  short8 aq0 = *(const short8*)&buf[(wave * 16 + l15) * 72 + quad * 8];
  short8 aq1 = *(const short8*)&buf[(wave * 16 + l15) * 72 + 32 + quad * 8];

  const float cexp = 0.18033688011112042f;  // log2(e) / sqrt(64)
  float rs[4] = {0.f, 0.f, 0.f, 0.f};

  // ---- pass 1: row sums, 128 keys per stage (rows 0..127 of buf) ----
  for (int kt = 0; kt < 16; kt++) {
    __syncthreads();
    {
      int c = t;
      #pragma unroll
      for (int it = 0; it < 4; it++, c += 256) {   // K tile: 128 keys x 64 d
        int r = c >> 3, cc = (c & 7) * 8;
        *(uint4*)&buf[r * 72 + cc] =
            *(const uint4*)&k2[(size_t)(b * SS + kt * 128 + r) * DM + h * DK + cc];
      }
    }
    __syncthreads();
    #pragma unroll
    for (int ct = 0; ct < 8; ct++) {
      floatx4 s = {};
      short8 bk0 = *(const short8*)&buf[(ct * 16 + l15) * 72 + quad * 8];
      short8 bk1 = *(const short8*)&buf[(ct * 16 + l15) * 72 + 32 + quad * 8];
      s = __builtin_amdgcn_mfma_f32_16x16x32_bf16(aq0, bk0, s, 0, 0, 0);
      s = __builtin_amdgcn_mfma_f32_16x16x32_bf16(aq1, bk1, s, 0, 0, 0);
      float m = (float)masku8[kt * 128 + ct * 16 + l15];
      #pragma unroll
      for (int r = 0; r < 4; r++) rs[r] += m * exp2f(s[r] * cexp);
    }
  }
  #pragma unroll
  for (int r = 0; r < 4; r++) {
    rs[r] += __shfl_xor(rs[r], 1);
    rs[r] += __shfl_xor(rs[r], 2);
    rs[r] += __shfl_xor(rs[r], 4);
    rs[r] += __shfl_xor(rs[r], 8);
  }
  if (l15 == 0) {
    #pragma unroll
    for (int r = 0; r < 4; r++)
      rowsum_inv[wave * 16 + quad * 4 + r] = rs[r] > 0.f ? 1.0f / rs[r] : 0.f;
  }
  __syncthreads();
  float rinv[4];
  #pragma unroll
  for (int r = 0; r < 4; r++) rinv[r] = rowsum_inv[wave * 16 + quad * 4 + r];

  floatx4 cacc[4] = {};
  const size_t attn_base = ((size_t)(h * BB + b) * SS + qt * 64) * SS;

  // ---- pass 2 (KVBLK=64): recompute, write normalized attn, accumulate PV ----
  for (int kt = 0; kt < 32; kt++) {
    __syncthreads();
    {
      int c = t;
      #pragma unroll
      for (int it = 0; it < 2; it++, c += 256) {   // K tile: rows 0..63
        int r = c >> 3, cc = (c & 7) * 8;
        *(uint4*)&buf[r * 72 + cc] =
            *(const uint4*)&k2[(size_t)(b * SS + kt * 64 + r) * DM + h * DK + cc];
      }
      c = t;
      #pragma unroll
      for (int it = 0; it < 2; it++, c += 256) {   // V^T tile: rows 64..127
        int n = c >> 3, cc = (c & 7) * 8;
        *(uint4*)&buf[VB + n * 72 + cc] =
            *(const uint4*)&vt[(size_t)(h * DK + n) * (BB * SS) + b * SS + kt * 64 + cc];
      }
    }
    __syncthreads();
    #pragma unroll
    for (int ct = 0; ct < 4; ct++) {
      floatx4 s = {};
      short8 bk0 = *(const short8*)&buf[(ct * 16 + l15) * 72 + quad * 8];
      short8 bk1 = *(const short8*)&buf[(ct * 16 + l15) * 72 + 32 + quad * 8];
      s = __builtin_amdgcn_mfma_f32_16x16x32_bf16(aq0, bk0, s, 0, 0, 0);
      s = __builtin_amdgcn_mfma_f32_16x16x32_bf16(aq1, bk1, s, 0, 0, 0);
      float m = (float)masku8[kt * 64 + ct * 16 + l15];
      #pragma unroll
      for (int r = 0; r < 4; r++) {
        float p = m * exp2f(s[r] * cexp) * rinv[r];      // normalized
        buf[PB + (wave * 16 + quad * 4 + r) * 72 + ct * 16 + l15] = f2bf(p);
      }
    }
    __syncthreads();
    // coalesced normalized fp32 attn write from LDS (64x64 tile, 4 float4/thread)
    {
      int c = t;
      #pragma unroll
      for (int it = 0; it < 4; it++, c += 256) {
        int r = c >> 4, fc = (c & 15) * 4;
        ushort4 u = *(const ushort4*)&buf[PB + r * 72 + fc];
        float4 f;
        f.x = bf2f(u.x); f.y = bf2f(u.y);
        f.z = bf2f(u.z); f.w = bf2f(u.w);
        *(float4*)&attns[attn_base + (size_t)r * SS + kt * 64 + fc] = f;
      }
    }
    // PV: cacc += P(64x64) @ V(64x64)
    #pragma unroll
    for (int ks = 0; ks < 2; ks++) {
      short8 ap = *(const short8*)&buf[PB + (wave * 16 + l15) * 72 + ks * 32 + quad * 8];
      #pragma unroll
      for (int ct = 0; ct < 4; ct++) {
        short8 bv = *(const short8*)&buf[VB + (ct * 16 + l15) * 72 + ks * 32 + quad * 8];
        cacc[ct] = __builtin_amdgcn_mfma_f32_16x16x32_bf16(ap, bv, cacc[ct], 0, 0, 0);
      }
    }
  }
  // epilogue: ctx[(b*S + q)*1024 + h*64 + n]  (bf16, already normalized)
  #pragma unroll
  for (int ct = 0; ct < 4; ct++)
    #pragma unroll
    for (int r = 0; r < 4; r++) {
      int row = b * SS + qt * 64 + wave * 16 + quad * 4 + r;
      int col = h * DK + ct * 16 + l15;
      ctx[(size_t)row * DM + col] = f2bf(cacc[ct][r]);
    }
}

// ---------------------------------------------------------------------------
extern "C" void kernel_launch(void* const* d_in, const int* in_sizes, int n_in,
                              void* d_out, int out_size, void* d_ws, size_t ws_size,
                              hipStream_t stream) {
  (void)in_sizes; (void)n_in; (void)out_size; (void)ws_size;
  const float* Q  = (const float*)d_in[0];
  const float* K  = (const float*)d_in[1];
  const float* V  = (const float*)d_in[2];
  const float* Wq = (const float*)d_in[3];
  const float* Wk = (const float*)d_in[4];
  const float* Wv = (const float*)d_in[5];
  const float* Wo = (const float*)d_in[6];
  const void* mask = d_in[7];

  float* out   = (float*)d_out;
  float* attns = out + (size_t)BB * SS * DM;  // after the 2x2048x1024 output

  char* ws = (char*)d_ws;
  unsigned short* Qb   = (unsigned short*)(ws);
  unsigned short* Kb   = (unsigned short*)(ws + (size_t)(8u  << 20));
  unsigned short* Vb   = (unsigned short*)(ws + (size_t)(16u << 20));
  unsigned short* q2   = (unsigned short*)(ws + (size_t)(24u << 20));
  unsigned short* k2   = (unsigned short*)(ws + (size_t)(32u << 20));
  unsigned short* vt   = (unsigned short*)(ws + (size_t)(40u << 20));
  unsigned short* ctx  = (unsigned short*)(ws + (size_t)(48u << 20));
  unsigned short* Wq_t = (unsigned short*)(ws + (size_t)(56u << 20));
  unsigned short* Wk_t = (unsigned short*)(ws + (size_t)(58u << 20));
  unsigned short* Wv_t = (unsigned short*)(ws + (size_t)(60u << 20));
  unsigned short* Wo_t = (unsigned short*)(ws + (size_t)(62u << 20));

  convert_qkv<<<dim3(4096, 3), 256, 0, stream>>>(Q, K, V, Qb, Kb, Vb);
  repack_w<<<dim3(16, 16, 4), 256, 0, stream>>>(Wq, Wk, Wv, Wo, Wq_t, Wk_t, Wv_t, Wo_t);
  gemm_bt<<<dim3(16, 32), 256, 0, stream>>>(Qb, Wq_t, q2, nullptr, 4096, 1024, 1024);
  gemm_bt<<<dim3(16, 32), 256, 0, stream>>>(Kb, Wk_t, k2, nullptr, 4096, 1024, 1024);
  gemm_bt<<<dim3(64, 8), 256, 0, stream>>>(Wv_t, Vb, vt, nullptr, 1024, 4096, 1024);
  attn_kernel<<<dim3(32, 2, 16), 256, 0, stream>>>(q2, k2, vt, mask, attns, ctx);
  gemm_bt<<<dim3(16, 32), 256, 0, stream>>>(ctx, Wo_t, nullptr, out, 4096, 1024, 1024);
}